// Round 3
// baseline (268.503 us; speedup 1.0000x reference)
//
#include <hip/hip_runtime.h>
#include <hip/hip_bf16.h>
#include <stdint.h>

#define NPIX 4096

typedef __attribute__((ext_vector_type(8))) short bf16x8;
typedef __attribute__((ext_vector_type(16))) float f32x16;
typedef __attribute__((ext_vector_type(4))) unsigned int uint4v;

__device__ __forceinline__ unsigned short bfb(float f) {
  __hip_bfloat16 h = __float2bfloat16(f);
  return __builtin_bit_cast(unsigned short, h);
}
__device__ __forceinline__ unsigned pack2(float a, float b) {
  return (unsigned)bfb(a) | ((unsigned)bfb(b) << 16);
}
__device__ __forceinline__ f32x16 mfma32(bf16x8 a, bf16x8 b, f32x16 c) {
  return __builtin_amdgcn_mfma_f32_32x32x16_bf16(a, b, c, 0, 0, 0);
}

// ---------------- kernel 0: convert weights to bf16 ----------------
__global__ void k_cvt(const float* __restrict__ Wq, const float* __restrict__ Wk,
                      const float* __restrict__ Wv, const float* __restrict__ Wr,
                      unsigned short* __restrict__ wqk, unsigned short* __restrict__ wv,
                      unsigned short* __restrict__ wr) {
  int i = blockIdx.x * 256 + threadIdx.x;  // 0..65535
  wqk[i] = bfb(i < 32768 ? Wq[i] : Wk[i - 32768]);
  wv[i]  = bfb(Wv[i]);
  wr[i]  = bfb(Wr[i]);
}

// ---------------- kernel 1: qkv projections ----------------
// out: qT [B][N][128] bf16, kT [B][N][128] bf16, v [B][256][N] bf16
__launch_bounds__(256, 2)
__global__ void k_qkv(const float* __restrict__ x,
                      const unsigned short* __restrict__ wqk,
                      const unsigned short* __restrict__ wv,
                      const float* __restrict__ bq, const float* __restrict__ bk,
                      const float* __restrict__ bv,
                      unsigned short* __restrict__ qT, unsigned short* __restrict__ kT,
                      unsigned short* __restrict__ vV) {
  __shared__ __align__(16) unsigned short xT[64 * 256];  // [n][c] bf16, swizzled rows of 512B
  const int b = blockIdx.x & 7;
  const int n0 = (blockIdx.x >> 3) * 64;
  const int t = threadIdx.x;
  const float* xb = x + (size_t)b * 256 * NPIX;
  #pragma unroll
  for (int p = 0; p < 16; ++p) {
    int c = (t >> 4) + p * 16;
    int nq = (t & 15) * 4;
    float4 f = *reinterpret_cast<const float4*>(xb + (size_t)c * NPIX + n0 + nq);
    float vals[4] = {f.x, f.y, f.z, f.w};
    #pragma unroll
    for (int j = 0; j < 4; ++j) {
      int n = nq + j;
      int byteoff = n * 512 + ((c * 2) ^ ((n & 7) << 4));
      xT[byteoff >> 1] = bfb(vals[j]);
    }
  }
  __syncthreads();
  const int lane = t & 63, w = t >> 6, l31 = lane & 31, hi = lane >> 5;
  f32x16 aq[2][2], av[2][2];
  #pragma unroll
  for (int a0 = 0; a0 < 2; ++a0)
    #pragma unroll
    for (int a1 = 0; a1 < 2; ++a1)
      #pragma unroll
      for (int i = 0; i < 16; ++i) { aq[a0][a1][i] = 0.f; av[a0][a1][i] = 0.f; }
  #pragma unroll
  for (int s = 0; s < 16; ++s) {  // K = 256 = 16 steps of 16
    bf16x8 xa[2];
    #pragma unroll
    for (int nt = 0; nt < 2; ++nt) {
      int n = nt * 32 + l31;
      int byteoff = n * 512 + (((s * 32 + hi * 16)) ^ ((n & 7) << 4));
      xa[nt] = *reinterpret_cast<const bf16x8*>(reinterpret_cast<const char*>(xT) + byteoff);
    }
    #pragma unroll
    for (int oc2 = 0; oc2 < 2; ++oc2) {
      int oc = w * 64 + oc2 * 32 + l31;
      bf16x8 wq = *reinterpret_cast<const bf16x8*>(wqk + oc * 256 + s * 16 + hi * 8);
      bf16x8 wvf = *reinterpret_cast<const bf16x8*>(wv + oc * 256 + s * 16 + hi * 8);
      #pragma unroll
      for (int nt = 0; nt < 2; ++nt) {
        aq[oc2][nt] = mfma32(xa[nt], wq, aq[oc2][nt]);   // D[n, oc]
        av[oc2][nt] = mfma32(wvf, xa[nt], av[oc2][nt]);  // D[vc, n]
      }
    }
  }
  #pragma unroll
  for (int oc2 = 0; oc2 < 2; ++oc2) {
    int oc = w * 64 + oc2 * 32 + l31;
    float bias = (oc < 128) ? bq[oc] : bk[oc - 128];
    unsigned short* dst = (oc < 128) ? (qT + (size_t)b * NPIX * 128 + oc)
                                     : (kT + (size_t)b * NPIX * 128 + (oc - 128));
    #pragma unroll
    for (int nt = 0; nt < 2; ++nt)
      #pragma unroll
      for (int r = 0; r < 16; ++r) {
        int n = n0 + nt * 32 + (r & 3) + 8 * (r >> 2) + 4 * hi;
        dst[(size_t)n * 128] = bfb(aq[oc2][nt][r] + bias);
      }
  }
  unsigned short* vb = vV + (size_t)b * 256 * NPIX;
  #pragma unroll
  for (int vc2 = 0; vc2 < 2; ++vc2)
    #pragma unroll
    for (int nt = 0; nt < 2; ++nt)
      #pragma unroll
      for (int r = 0; r < 16; ++r) {
        int vc = w * 64 + vc2 * 32 + (r & 3) + 8 * (r >> 2) + 4 * hi;
        int n = n0 + nt * 32 + l31;
        vb[(size_t)vc * NPIX + n] = bfb(av[vc2][nt][r] + bv[vc]);
      }
}

// ---------------- kernel 2: fused flash attention, intra-block split-K ----------------
// 512 threads = 8 waves: waves 0-3 do keys [0,2048), waves 4-7 do [2048,4096).
// S^T = K^T Q (swapped), online softmax over keys, O^T = V P^T; LDS merge at end.
__launch_bounds__(512, 2)
__global__ void k_attn(const unsigned short* __restrict__ qT,
                       const unsigned short* __restrict__ kT,
                       const unsigned short* __restrict__ vV,
                       unsigned short* __restrict__ oT) {
  __shared__ __align__(16) char smem[98304];  // 2 x (K 16KB + V 32KB)
  const int b = blockIdx.x & 7;          // XCD-affine: one batch per XCD
  const int qt = blockIdx.x >> 3;
  const int t = threadIdx.x, lane = t & 63, l31 = lane & 31, hi = lane >> 5;
  const int w = t >> 6, h = w >> 2, sw = w & 3;
  char* Kl = smem + h * 49152;
  char* Vl = smem + h * 49152 + 16384;
  const int qp = qt * 128 + sw * 32 + l31;
  const unsigned short* qTb = qT + (size_t)b * NPIX * 128;
  const unsigned short* kTb = kT + (size_t)b * NPIX * 128;
  const unsigned short* vb  = vV + (size_t)b * 256 * NPIX;
  bf16x8 qf[8];
  #pragma unroll
  for (int s = 0; s < 8; ++s)
    qf[s] = *reinterpret_cast<const bf16x8*>(qTb + (size_t)qp * 128 + s * 16 + hi * 8);
  f32x16 O[8];
  #pragma unroll
  for (int vt = 0; vt < 8; ++vt)
    #pragma unroll
    for (int i = 0; i < 16; ++i) O[vt][i] = 0.f;
  float m_run = -3.0e38f, l_run = 0.0f;

  for (int kt2 = 0; kt2 < 32; ++kt2) {
    const int kp0 = (h * 32 + kt2) * 64;
    // stage K tile [64][128] bf16 (swizzled dest)
    #pragma unroll
    for (int i = 0; i < 4; ++i) {
      int row = sw * 16 + i * 4 + (lane >> 4);
      int c2 = (lane & 15) * 16;
      uint4v d = *reinterpret_cast<const uint4v*>(
          reinterpret_cast<const char*>(kTb) + (size_t)(kp0 + row) * 256 + c2);
      *reinterpret_cast<uint4v*>(Kl + row * 256 + (c2 ^ ((row & 7) << 4))) = d;
    }
    // stage V tile [256][64] bf16
    #pragma unroll
    for (int i = 0; i < 8; ++i) {
      int vc = sw * 64 + i * 8 + (lane >> 3);
      int c2 = (lane & 7) * 16;
      uint4v d = *reinterpret_cast<const uint4v*>(
          reinterpret_cast<const char*>(vb) + (size_t)vc * 8192 + kp0 * 2 + c2);
      *reinterpret_cast<uint4v*>(Vl + vc * 128 + (c2 ^ ((vc & 7) << 4))) = d;
    }
    __syncthreads();
    #pragma unroll
    for (int rt = 0; rt < 2; ++rt) {
      f32x16 S;
      #pragma unroll
      for (int i = 0; i < 16; ++i) S[i] = 0.f;
      __builtin_amdgcn_s_setprio(1);
      #pragma unroll
      for (int s = 0; s < 8; ++s) {  // d = 128 = 8 steps
        int row = rt * 32 + l31;
        int byteoff = row * 256 + ((s * 32 + hi * 16) ^ ((row & 7) << 4));
        bf16x8 ka = *reinterpret_cast<const bf16x8*>(Kl + byteoff);
        S = mfma32(ka, qf[s], S);  // S^T[kp][qp]
      }
      __builtin_amdgcn_s_setprio(0);
      // key-wise max: in-lane 16 + partner lane^32 (verified shfl path)
      float mx = fmaxf(fmaxf(fmaxf(S[0], S[1]), fmaxf(S[2], S[3])),
                       fmaxf(fmaxf(S[4], S[5]), fmaxf(S[6], S[7])));
      mx = fmaxf(mx, fmaxf(fmaxf(fmaxf(S[8], S[9]), fmaxf(S[10], S[11])),
                           fmaxf(fmaxf(S[12], S[13]), fmaxf(S[14], S[15]))));
      mx = fmaxf(mx, __shfl_xor(mx, 32));
      if (__any(mx > m_run + 8.0f)) {  // defer-max (T13)
        float mn = fmaxf(m_run, mx);
        float al = __expf(m_run - mn);
        l_run *= al;
        #pragma unroll
        for (int vt = 0; vt < 8; ++vt)
          #pragma unroll
          for (int i = 0; i < 16; ++i) O[vt][i] *= al;
        m_run = mn;
      }
      float p[16], sum = 0.f;
      #pragma unroll
      for (int i = 0; i < 16; ++i) { p[i] = __expf(S[i] - m_run); sum += p[i]; }
      sum += __shfl_xor(sum, 32);
      l_run += sum;
      // pack P to bf16 fragments: pairs + half swaps (verified shfl path)
      unsigned wd[8];
      #pragma unroll
      for (int i = 0; i < 8; ++i) wd[i] = pack2(p[2 * i], p[2 * i + 1]);
      #pragma unroll
      for (int pr = 0; pr < 4; ++pr) {
        int ia = (pr & 1) + (pr >> 1) * 4;      // 0,1,4,5
        int ib = ia + 2;                         // 2,3,6,7
        unsigned xs = (unsigned)__shfl_xor((int)wd[ia], 32);
        unsigned ys = (unsigned)__shfl_xor((int)wd[ib], 32);
        unsigned na = hi ? ys : wd[ia];
        unsigned nb = hi ? wd[ib] : xs;
        wd[ia] = na; wd[ib] = nb;
      }
      bf16x8 pf[2];
      { uint4v u; u.x = wd[0]; u.y = wd[1]; u.z = wd[2]; u.w = wd[3];
        pf[0] = __builtin_bit_cast(bf16x8, u); }
      { uint4v u; u.x = wd[4]; u.y = wd[5]; u.z = wd[6]; u.w = wd[7];
        pf[1] = __builtin_bit_cast(bf16x8, u); }
      // PV: O^T[vc][qp] += V[vc,kp] * P^T[kp,qp]
      __builtin_amdgcn_s_setprio(1);
      #pragma unroll
      for (int sl = 0; sl < 2; ++sl) {
        #pragma unroll
        for (int vt = 0; vt < 8; ++vt) {
          int vc = vt * 32 + l31;
          int byteoff = vc * 128 + (((rt * 2 + sl) * 32 + hi * 16) ^ ((vc & 7) << 4));
          bf16x8 va = *reinterpret_cast<const bf16x8*>(Vl + byteoff);
          O[vt] = mfma32(va, pf[sl], O[vt]);
        }
      }
      __builtin_amdgcn_s_setprio(0);
    }
    __syncthreads();
  }
  // ---- merge the two key-halves through LDS ----
  float4* shf = (float4*)smem;                 // 64KB: [vt4][i4][sw][lane] float4
  float* ml = (float*)(smem + 65536);          // 2KB:  [2][sw*64+lane]
  float a0 = 1.f, a1 = 0.f, rl = 1.f;
  #pragma unroll 2
  for (int round = 0; round < 2; ++round) {
    if (h == 1) {
      #pragma unroll
      for (int vt4 = 0; vt4 < 4; ++vt4)
        #pragma unroll
        for (int i4 = 0; i4 < 4; ++i4) {
          float4 f;
          f.x = O[round * 4 + vt4][i4 * 4];
          f.y = O[round * 4 + vt4][i4 * 4 + 1];
          f.z = O[round * 4 + vt4][i4 * 4 + 2];
          f.w = O[round * 4 + vt4][i4 * 4 + 3];
          shf[((vt4 * 4 + i4) * 4 + sw) * 64 + lane] = f;
        }
      if (round == 0) { ml[sw * 64 + lane] = m_run; ml[256 + sw * 64 + lane] = l_run; }
    }
    __syncthreads();
    if (h == 0) {
      if (round == 0) {
        float m1 = ml[sw * 64 + lane], l1 = ml[256 + sw * 64 + lane];
        float m = fmaxf(m_run, m1);
        a0 = __expf(m_run - m);
        a1 = __expf(m1 - m);
        rl = 1.0f / (l_run * a0 + l1 * a1);
      }
      #pragma unroll
      for (int vt4 = 0; vt4 < 4; ++vt4)
        #pragma unroll
        for (int i4 = 0; i4 < 4; ++i4) {
          float4 f = shf[((vt4 * 4 + i4) * 4 + sw) * 64 + lane];
          O[round * 4 + vt4][i4 * 4]     = O[round * 4 + vt4][i4 * 4] * a0     + f.x * a1;
          O[round * 4 + vt4][i4 * 4 + 1] = O[round * 4 + vt4][i4 * 4 + 1] * a0 + f.y * a1;
          O[round * 4 + vt4][i4 * 4 + 2] = O[round * 4 + vt4][i4 * 4 + 2] * a0 + f.z * a1;
          O[round * 4 + vt4][i4 * 4 + 3] = O[round * 4 + vt4][i4 * 4 + 3] * a0 + f.w * a1;
        }
    }
    __syncthreads();
  }
  if (h == 0) {
    unsigned short* oTb = oT + (size_t)b * NPIX * 256;  // [qp][vc]
    #pragma unroll
    for (int vt = 0; vt < 8; ++vt)
      #pragma unroll
      for (int i = 0; i < 16; i += 2) {
        int vc = vt * 32 + (i & 3) + 8 * (i >> 2) + 4 * hi;
        unsigned pk = pack2(O[vt][i] * rl, O[vt][i + 1] * rl);
        *reinterpret_cast<unsigned*>(oTb + (size_t)qp * 256 + vc) = pk;
      }
  }
}

// ---------------- kernel 3: output projection + residual ----------------
__launch_bounds__(256, 2)
__global__ void k_out(const unsigned short* __restrict__ oT,
                      const unsigned short* __restrict__ wr,
                      const float* __restrict__ br, const float* __restrict__ gamma,
                      const float* __restrict__ x, float* __restrict__ out) {
  const int b = blockIdx.x & 7;
  const int n0 = (blockIdx.x >> 3) * 64;
  const int t = threadIdx.x, w = t >> 6, lane = t & 63, l31 = lane & 31, hi = lane >> 5;
  const unsigned short* oTb = oT + (size_t)b * NPIX * 256;
  f32x16 acc[2][2];
  #pragma unroll
  for (int a0 = 0; a0 < 2; ++a0)
    #pragma unroll
    for (int a1 = 0; a1 < 2; ++a1)
      #pragma unroll
      for (int i = 0; i < 16; ++i) acc[a0][a1][i] = 0.f;
  #pragma unroll
  for (int s = 0; s < 16; ++s) {  // K = 256 (vc)
    bf16x8 ofr[2], wfr[2];
    #pragma unroll
    for (int nt = 0; nt < 2; ++nt) {
      int n = n0 + nt * 32 + l31;
      ofr[nt] = *reinterpret_cast<const bf16x8*>(oTb + (size_t)n * 256 + s * 16 + hi * 8);
    }
    #pragma unroll
    for (int c2 = 0; c2 < 2; ++c2) {
      int c = w * 64 + c2 * 32 + l31;
      wfr[c2] = *reinterpret_cast<const bf16x8*>(wr + c * 256 + s * 16 + hi * 8);
    }
    #pragma unroll
    for (int c2 = 0; c2 < 2; ++c2)
      #pragma unroll
      for (int nt = 0; nt < 2; ++nt)
        acc[c2][nt] = mfma32(wfr[c2], ofr[nt], acc[c2][nt]);  // D[c, n]
  }
  float g = gamma[0];
  #pragma unroll
  for (int c2 = 0; c2 < 2; ++c2)
    #pragma unroll
    for (int nt = 0; nt < 2; ++nt)
      #pragma unroll
      for (int r = 0; r < 16; ++r) {
        int c = w * 64 + c2 * 32 + (r & 3) + 8 * (r >> 2) + 4 * hi;
        int n = n0 + nt * 32 + l31;
        size_t idx = (size_t)b * 256 * NPIX + (size_t)c * NPIX + n;
        out[idx] = g * (acc[c2][nt][r] + br[c]) + x[idx];
      }
}

extern "C" void kernel_launch(void* const* d_in, const int* in_sizes, int n_in,
                              void* d_out, int out_size, void* d_ws, size_t ws_size,
                              hipStream_t stream) {
  const float* x     = (const float*)d_in[0];
  const float* Wk    = (const float*)d_in[1];
  const float* bk    = (const float*)d_in[2];
  const float* Wq    = (const float*)d_in[3];
  const float* bq    = (const float*)d_in[4];
  const float* Wv    = (const float*)d_in[5];
  const float* bv    = (const float*)d_in[6];
  const float* Wr    = (const float*)d_in[7];
  const float* br    = (const float*)d_in[8];
  const float* gamma = (const float*)d_in[9];

  const size_t OFF_QT  = 0;
  const size_t OFF_KT  = 8388608;
  const size_t OFF_V   = 16777216;
  const size_t OFF_OT  = 33554432;
  const size_t OFF_WQK = 50331648;
  const size_t OFF_WV  = 50462720;
  const size_t OFF_WR  = 50593792;
  const size_t NEED    = 50724864;
  if (ws_size < NEED) return;  // cannot run without scratch

  char* ws = (char*)d_ws;
  unsigned short* qT  = (unsigned short*)(ws + OFF_QT);
  unsigned short* kT  = (unsigned short*)(ws + OFF_KT);
  unsigned short* vV  = (unsigned short*)(ws + OFF_V);
  unsigned short* oT  = (unsigned short*)(ws + OFF_OT);
  unsigned short* wqk = (unsigned short*)(ws + OFF_WQK);
  unsigned short* wvb = (unsigned short*)(ws + OFF_WV);
  unsigned short* wrb = (unsigned short*)(ws + OFF_WR);

  k_cvt<<<256, 256, 0, stream>>>(Wq, Wk, Wv, Wr, wqk, wvb, wrb);
  k_qkv<<<512, 256, 0, stream>>>(x, wqk, wvb, bq, bk, bv, qT, kT, vV);
  k_attn<<<256, 512, 0, stream>>>(qT, kT, vV, oT);
  k_out<<<512, 256, 0, stream>>>(oT, wrb, br, gamma, x, (float*)d_out);
}